// Round 1
// baseline (236.107 us; speedup 1.0000x reference)
//
#include <hip/hip_runtime.h>
#include <math.h>

#define NB    16
#define NAg   3
#define NCg   85
#define NCLS  80
#define NGg   76
#define NSp   (NGg*NGg)     // 5776
#define NBOX  50
#define INCH  256

// ws layout (bytes)
#define ACC_OFF  0                       // 8 floats  (loss accumulators)
#define HAS_OFF  32                      // 16 ints   (per-batch has_boxes flag)
#define WT_OFF   128                     // 256*16 floats = 16384 B (transposed W, stride 16)
#define GB_OFF   (WT_OFF + 16384)        // NB*NBOX*8 floats = 25600 B (IoU box records)
#define GA_OFF   (GB_OFF + 25600)        // NB*NBOX*8 floats = 25600 B (target aux)
#define GI_OFF   (GA_OFF + 25600)        // NB*NBOX*2 ints   =  6400 B (cell, cls)
#define ZERO_BYTES 96                    // acc + hasAny only

__device__ __constant__ float c_AW[9] = {1.25f,2.0f,4.125f,3.75f,7.75f,7.375f,14.5f,19.5f,46.625f};
__device__ __constant__ float c_AH[9] = {1.625f,3.75f,2.875f,7.625f,5.625f,14.875f,11.25f,24.75f,40.75f};

__device__ __forceinline__ float safe_log(float p) {
    return fmaxf(logf(fmaxf(p, 1e-12f)), -100.0f);
}
__device__ __forceinline__ float sigm(float x) {
    return 1.0f / (1.0f + expf(-x));
}

// ---- Kernel 1: label processing + W transpose -----------------------------
// grid 16x256 = 4096 threads: all do Wt transpose, first 800 also do labels.
__global__ __launch_bounds__(256) void k_labels(
    const float* __restrict__ labels, const float* __restrict__ W,
    float* __restrict__ Wt, float* __restrict__ gbox, float* __restrict__ gaux,
    int* __restrict__ gint, int* __restrict__ hasAny)
{
    const int t = blockIdx.x * 256 + threadIdx.x;

    // transposed weights: Wt[c*16 + f] = W[row(f)*INCH + c], f<15 (slot 15 = pad)
    if (t < INCH * 16) {
        const int c = t >> 4, f = t & 15;
        Wt[t] = (f < 15) ? W[((f / 5) * NCg + (f % 5)) * INCH + c] : 0.f;
    }
    if (t >= NB * NBOX) return;
    const int b = t / NBOX;

    const float* L = labels + (size_t)t * 5;
    const float l0 = L[0], l1 = L[1], l2 = L[2], l3 = L[3], l4 = L[4];
    const int valid = (l0 + l1 + l2 + l3 + l4) > 0.f;

    const float gx = l1 * NGg, gy = l2 * NGg, gw = l3 * NGg, gh = l4 * NGg;

    int best = 0; float brr = -1.f;
#pragma unroll
    for (int k = 0; k < 9; k++) {
        float inter = fminf(gw, c_AW[k]) * fminf(gh, c_AH[k]);
        float uni   = gw*gh + c_AW[k]*c_AH[k] - inter;
        float r     = inter / uni;
        if (r > brr) { brr = r; best = k; }   // first max wins (argmax)
    }
    const int a = (best <= 2) ? best : -1;
    const int assign = valid && (a >= 0);
    const int a_safe = a < 0 ? 0 : (a > 2 ? 2 : a);

    const int gi = (int)floorf(gx), gj = (int)floorf(gy);
    const int inb = (gi >= 0) && (gi < NGg) && (gj >= 0) && (gj < NGg);
    const int cell = (assign && inb) ? (a * NSp + gj * NGg + gi) : -1;

    float* gb = gbox + (size_t)t * 8;
    gb[0] = gx - gw * 0.5f;             // x0
    gb[1] = gy - gh * 0.5f;             // y0
    gb[2] = gx + gw * 0.5f;             // x1
    gb[3] = gy + gh * 0.5f;             // y1
    gb[4] = valid ? gw * gh : -1.f;     // area, <0 => skip in IoU
    gb[5] = __int_as_float(cell);       // assigned cell (-1 none)

    float* ga = gaux + (size_t)t * 8;
    ga[0] = gx - floorf(gx);
    ga[1] = gy - floorf(gy);
    ga[2] = logf(gw / c_AW[a_safe] + 1e-16f);
    ga[3] = logf(gh / c_AH[a_safe] + 1e-16f);
    ga[4] = 2.f - gw * gh / (float)NSp;

    gint[t*2 + 0] = cell;
    gint[t*2 + 1] = (int)l0;

    if (valid) atomicOr(&hasAny[b], 1);
}

// ---- Kernel 2: fused 15-ch GEMM + decode + IoU-threshold + obj BCE --------
// one wave per block, one spatial position per thread (all 3 anchors).
__global__ __launch_bounds__(64) void k_main(
    const float* __restrict__ xin, const float* __restrict__ Wt,
    const float* __restrict__ bias, const float* __restrict__ gbox,
    const int* __restrict__ hasAny, float* __restrict__ acc)
{
    const int b = blockIdx.y;
    const int s = blockIdx.x * 64 + threadIdx.x;

    float l = 0.f;
    if (s < NSp) {
        float accv[15];
#pragma unroll
        for (int f = 0; f < 15; ++f) accv[f] = 0.f;

        const float* xp = xin + (size_t)b * INCH * NSp + s;
        // 8 global loads in flight; W rows are wave-uniform -> s_load_dwordx16
#pragma unroll 2
        for (int c0 = 0; c0 < INCH; c0 += 8) {
            float v[8];
#pragma unroll
            for (int k = 0; k < 8; ++k) v[k] = xp[(size_t)(c0 + k) * NSp];
#pragma unroll
            for (int k = 0; k < 8; ++k) {
                const float* wr = Wt + ((c0 + k) << 4);
#pragma unroll
                for (int f = 0; f < 15; ++f) accv[f] += wr[f] * v[k];
            }
        }

        const int sy = s / NGg;
        const int sx = s - sy * NGg;
        const float gxf = (float)sx, gyf = (float)sy;

        float pbx0[3], pby0[3], pbx1[3], pby1[3], pa[3], cf[3];
#pragma unroll
        for (int a = 0; a < 3; ++a) {
            const float px = sigm(accv[a*5+0] + bias[a*NCg+0]) + gxf;
            const float py = sigm(accv[a*5+1] + bias[a*NCg+1]) + gyf;
            const float pw = expf(accv[a*5+2] + bias[a*NCg+2]) * c_AW[a];
            const float ph = expf(accv[a*5+3] + bias[a*NCg+3]) * c_AH[a];
            cf[a]  = sigm(accv[a*5+4] + bias[a*NCg+4]);
            pbx0[a] = px - pw * 0.5f;  pby0[a] = py - ph * 0.5f;
            pbx1[a] = px + pw * 0.5f;  pby1[a] = py + ph * 0.5f;
            pa[a]   = pw * ph;
        }

        bool ex0 = false, ex1 = false, ex2 = false;   // any IoU > 0.7
        bool as0 = false, as1 = false, as2 = false;   // cell assigned
        const float* gb = gbox + (size_t)b * NBOX * 8;
        for (int n = 0; n < NBOX; ++n) {
            const float bx0 = gb[n*8+0], by0 = gb[n*8+1];
            const float bx1 = gb[n*8+2], by1 = gb[n*8+3];
            const float gar = gb[n*8+4];
            const int cell  = __float_as_int(gb[n*8+5]);
            const int d = cell - s;
            as0 = as0 || (d == 0);
            as1 = as1 || (d == NSp);
            as2 = as2 || (d == 2*NSp);
            if (gar >= 0.f) {                         // wave-uniform branch
#pragma unroll
                for (int a = 0; a < 3; ++a) {
                    const float tlx = fmaxf(pbx0[a], bx0);
                    const float tly = fmaxf(pby0[a], by0);
                    const float brx = fminf(pbx1[a], bx1);
                    const float bry = fminf(pby1[a], by1);
                    const float dx = brx - tlx, dy = bry - tly;
                    const float inter = (dx > 0.f && dy > 0.f) ? dx * dy : 0.f;
                    // iou > 0.7  <=>  inter > 0.7*(union)   (no division)
                    const bool hit = inter > 0.7f * (pa[a] + gar - inter);
                    if      (a == 0) ex0 = ex0 || hit;
                    else if (a == 1) ex1 = ex1 || hit;
                    else             ex2 = ex2 || hit;
                }
            }
        }

        const bool hasB = hasAny[b] != 0;
#pragma unroll
        for (int a = 0; a < 3; ++a) {
            const bool ex = (a == 0) ? ex0 : ((a == 1) ? ex1 : ex2);
            const bool as = (a == 0) ? as0 : ((a == 1) ? as1 : as2);
            const bool maskpre = hasB ? (!ex) : true;
            if (maskpre || as) {
                const float c = cf[a];
                l += as ? -safe_log(c) : -safe_log(1.f - c);
            }
        }
    }

    // single-wave block: shuffle reduce, one atomic
#pragma unroll
    for (int off = 32; off > 0; off >>= 1) l += __shfl_down(l, off);
    if (threadIdx.x == 0) atomicAdd(&acc[2], l);
}

// ---- Kernel 3: per-assigned-cell xy/wh/cls losses -------------------------
__global__ __launch_bounds__(256) void k_assigned(
    const float* __restrict__ xin, const float* __restrict__ W,
    const float* __restrict__ bias, const float* __restrict__ gaux,
    const int* __restrict__ gint, float* __restrict__ acc)
{
    const int t = blockIdx.x;            // box id 0..799
    const int b = t / NBOX, n = t % NBOX;
    const int cell = gint[t*2];
    if (cell < 0) return;
    // winner = highest box index sharing this cell (== old atomicMax semantics)
    for (int n2 = n + 1; n2 < NBOX; ++n2)
        if (gint[(b*NBOX + n2)*2] == cell) return;

    const int a = cell / NSp, s = cell % NSp;
    const int o0 = a * NCg;
    const int tid = threadIdx.x;

    __shared__ float4 col4[64];
    __shared__ float  xsh[NCg];
    __shared__ float  sacc[3];

    ((float*)col4)[tid] = xin[((size_t)b * INCH + tid) * NSp + s];
    if (tid < 3) sacc[tid] = 0.f;
    __syncthreads();

    const int wid = tid >> 6, lane = tid & 63;
    for (int o = wid; o < NCg; o += 4) {
        const float4 wv = *(const float4*)&W[(size_t)(o0 + o) * INCH + lane * 4];
        const float4 cv = col4[lane];
        float p = wv.x*cv.x + wv.y*cv.y + wv.z*cv.z + wv.w*cv.w;
        for (int off = 32; off; off >>= 1) p += __shfl_down(p, off);
        if (lane == 0) xsh[o] = p + bias[o0 + o];
    }
    __syncthreads();

    if (tid < NCg) {
        const float* ga = gaux + (size_t)t * 8;
        const float sval = ga[4];
        const int gcls = gint[t*2 + 1];
        float val = xsh[tid];
        float term; int slot;
        if (tid < 2) {                       // xy BCE * sval
            float tgt = ga[tid];
            float p = sigm(val);
            term = -(tgt * safe_log(p) + (1.f - tgt) * safe_log(1.f - p)) * sval;
            slot = 0;
        } else if (tid < 4) {                // wh MSE * 0.5*sval
            float tgt = ga[tid];             // ga[2], ga[3]
            float d = val - tgt;
            term = 0.5f * sval * d * d;
            slot = 1;
        } else if (tid == 4) {               // conf handled in k_main
            term = 0.f; slot = 2;
        } else {                             // cls BCE
            float tgt = ((tid - 5) == gcls) ? 1.f : 0.f;
            float p = sigm(val);
            term = -(tgt * safe_log(p) + (1.f - tgt) * safe_log(1.f - p));
            slot = 2;
        }
        atomicAdd(&sacc[slot], term);
    }
    __syncthreads();
    if (tid == 0) {
        atomicAdd(&acc[0], sacc[0]);
        atomicAdd(&acc[1], sacc[1]);
        atomicAdd(&acc[3], sacc[2]);
    }
}

// ---- Kernel 4: finalize ---------------------------------------------------
__global__ void k_final(const float* __restrict__ acc, float* __restrict__ out)
{
    float xy = acc[0], wh = acc[1], ob = acc[2], cl = acc[3];
    out[0] = xy + wh + ob + cl;
    out[1] = xy; out[2] = wh; out[3] = ob; out[4] = cl;
}

extern "C" void kernel_launch(void* const* d_in, const int* in_sizes, int n_in,
                              void* d_out, int out_size, void* d_ws, size_t ws_size,
                              hipStream_t stream)
{
    const float* xin    = (const float*)d_in[0];
    const float* labels = (const float*)d_in[1];
    const float* W      = (const float*)d_in[2];
    const float* bias   = (const float*)d_in[3];

    char* ws = (char*)d_ws;
    float* acc    = (float*)(ws + ACC_OFF);
    int*   hasAny = (int*)  (ws + HAS_OFF);
    float* Wt     = (float*)(ws + WT_OFF);
    float* gbox   = (float*)(ws + GB_OFF);
    float* gaux   = (float*)(ws + GA_OFF);
    int*   gint   = (int*)  (ws + GI_OFF);
    float* out    = (float*)d_out;

    hipMemsetAsync(ws, 0, ZERO_BYTES, stream);   // acc + hasAny (96 B)

    k_labels<<<16, 256, 0, stream>>>(labels, W, Wt, gbox, gaux, gint, hasAny);

    k_main<<<dim3((NSp + 63) / 64, NB), 64, 0, stream>>>(xin, Wt, bias, gbox, hasAny, acc);

    k_assigned<<<dim3(NB * NBOX), 256, 0, stream>>>(xin, W, bias, gaux, gint, acc);

    k_final<<<1, 1, 0, stream>>>(acc, out);
}

// Round 2
// 231.727 us; speedup vs baseline: 1.0189x; 1.0189x over previous
//
#include <hip/hip_runtime.h>
#include <math.h>

#define NB    16
#define NAg   3
#define NCg   85
#define NCLS  80
#define NGg   76
#define NSp   (NGg*NGg)     // 5776
#define NBOX  50
#define INCH  256

// ws layout (bytes)
#define ACC_OFF  0                       // 8 floats  (loss accumulators)
#define HAS_OFF  32                      // 16 ints   (per-batch has_boxes flag)
#define WT_OFF   128                     // 256*16 floats = 16384 B (transposed W, stride 16)
#define GB_OFF   (WT_OFF + 16384)        // NB*NBOX*8 floats = 25600 B (IoU box records)
#define GA_OFF   (GB_OFF + 25600)        // NB*NBOX*8 floats = 25600 B (target aux)
#define GI_OFF   (GA_OFF + 25600)        // NB*NBOX*2 ints   =  6400 B (cell, cls)

__device__ __constant__ float c_AW[9] = {1.25f,2.0f,4.125f,3.75f,7.75f,7.375f,14.5f,19.5f,46.625f};
__device__ __constant__ float c_AH[9] = {1.625f,3.75f,2.875f,7.625f,5.625f,14.875f,11.25f,24.75f,40.75f};

__device__ __forceinline__ float safe_log(float p) {
    return fmaxf(logf(fmaxf(p, 1e-12f)), -100.0f);
}
__device__ __forceinline__ float sigm(float x) {
    return 1.0f / (1.0f + expf(-x));
}

// ---- Kernel 1: label processing + W transpose + acc/hasAny init -----------
// grid 16 blocks x 256: block b handles batch b's 50 boxes; all threads
// cooperate on the Wt transpose; block 0 zeroes acc (no memset dispatch).
__global__ __launch_bounds__(256) void k_labels(
    const float* __restrict__ labels, const float* __restrict__ W,
    float* __restrict__ Wt, float* __restrict__ gbox, float* __restrict__ gaux,
    int* __restrict__ gint, int* __restrict__ hasAny, float* __restrict__ acc)
{
    const int b = blockIdx.x, tid = threadIdx.x;
    const int t = b * 256 + tid;

    // transposed weights: Wt[c*16 + f] = W[row(f)*INCH + c], f<15 (slot 15 pad)
    {
        const int c = t >> 4, f = t & 15;
        Wt[t] = (f < 15) ? W[((f / 5) * NCg + (f % 5)) * INCH + c] : 0.f;
    }
    if (b == 0 && tid < 8) acc[tid] = 0.f;

    int valid = 0;
    if (tid < NBOX) {
        const int bt = b * NBOX + tid;
        const float* L = labels + (size_t)bt * 5;
        const float l0 = L[0], l1 = L[1], l2 = L[2], l3 = L[3], l4 = L[4];
        valid = (l0 + l1 + l2 + l3 + l4) > 0.f;

        const float gx = l1 * NGg, gy = l2 * NGg, gw = l3 * NGg, gh = l4 * NGg;

        int best = 0; float brr = -1.f;
#pragma unroll
        for (int k = 0; k < 9; k++) {
            float inter = fminf(gw, c_AW[k]) * fminf(gh, c_AH[k]);
            float uni   = gw*gh + c_AW[k]*c_AH[k] - inter;
            float r     = inter / uni;
            if (r > brr) { brr = r; best = k; }   // first max wins (argmax)
        }
        const int a = (best <= 2) ? best : -1;
        const int assign = valid && (a >= 0);
        const int a_safe = a < 0 ? 0 : (a > 2 ? 2 : a);

        const int gi = (int)floorf(gx), gj = (int)floorf(gy);
        const int inb = (gi >= 0) && (gi < NGg) && (gj >= 0) && (gj < NGg);
        const int cell = (assign && inb) ? (a * NSp + gj * NGg + gi) : -1;

        float* gb = gbox + (size_t)bt * 8;
        gb[0] = gx - gw * 0.5f;             // x0
        gb[1] = gy - gh * 0.5f;             // y0
        gb[2] = gx + gw * 0.5f;             // x1
        gb[3] = gy + gh * 0.5f;             // y1
        gb[4] = valid ? gw * gh : -1.f;     // area, <0 => skip in IoU
        gb[5] = __int_as_float(cell);       // assigned cell (-1 none)

        float* ga = gaux + (size_t)bt * 8;
        ga[0] = gx - floorf(gx);
        ga[1] = gy - floorf(gy);
        ga[2] = logf(gw / c_AW[a_safe] + 1e-16f);
        ga[3] = logf(gh / c_AH[a_safe] + 1e-16f);
        ga[4] = 2.f - gw * gh / (float)NSp;

        gint[bt*2 + 0] = cell;
        gint[bt*2 + 1] = (int)l0;
    }
    // hasAny via wave-0 ballot (lanes 0..49 carry valid flags), plain store
    if (tid < 64) {
        const unsigned long long m = __ballot(valid != 0);
        if (tid == 0) hasAny[b] = (m != 0ULL) ? 1 : 0;
    }
}

// ---- Kernel 2: fused 15-ch GEMM + decode + IoU-threshold + obj BCE --------
// 256-thread block = 4 waves. Block covers 64 spatial positions; wave w
// reduces channels [64w, 64w+64), partials combined in LDS. IoU boxes are
// split across waves (n = w, w+4, ...), flags OR-combined via LDS bitmask.
__global__ __launch_bounds__(256) void k_main(
    const float* __restrict__ xin, const float* __restrict__ Wt,
    const float* __restrict__ bias, const float* __restrict__ gbox,
    const int* __restrict__ hasAny, float* __restrict__ acc)
{
    __shared__ float partial[15 * 256];   // [f][w*64 + l]
    __shared__ float red[15 * 64];        // [f][l]
    __shared__ int   smask[256];

    const int b   = blockIdx.y;
    const int tid = threadIdx.x;
    const int w   = tid >> 6, l = tid & 63;
    const int s   = blockIdx.x * 64 + l;
    const bool live = (s < NSp);

    float accv[15];
#pragma unroll
    for (int f = 0; f < 15; ++f) accv[f] = 0.f;

    if (live) {
        const float* xp = xin + ((size_t)b * INCH + w * 64) * NSp + s;
        const float* wp = Wt + (w * 64) * 16;
#pragma unroll 2
        for (int c0 = 0; c0 < 64; c0 += 8) {
            float v[8];
#pragma unroll
            for (int k = 0; k < 8; ++k) v[k] = xp[(size_t)(c0 + k) * NSp];
#pragma unroll
            for (int k = 0; k < 8; ++k) {
                const float* wr = wp + ((c0 + k) << 4);  // wave-uniform -> s_load
#pragma unroll
                for (int f = 0; f < 15; ++f) accv[f] += wr[f] * v[k];
            }
        }
    }
#pragma unroll
    for (int f = 0; f < 15; ++f) partial[f * 256 + tid] = accv[f];
    __syncthreads();

    // cross-wave reduce: thread (w,l) sums f in {w, w+4, w+8, w+12}
    for (int f = w; f < 15; f += 4) {
        red[f * 64 + l] = partial[f * 256 + l]       + partial[f * 256 + 64 + l]
                        + partial[f * 256 + 128 + l] + partial[f * 256 + 192 + l];
    }
    __syncthreads();

    float cf[3];
    int mask = 0;
    if (live) {
        const int sy = s / NGg;
        const int sx = s - sy * NGg;
        const float gxf = (float)sx, gyf = (float)sy;

        float pbx0[3], pby0[3], pbx1[3], pby1[3], pa[3];
#pragma unroll
        for (int a = 0; a < 3; ++a) {
            const float x0 = red[(a*5+0) * 64 + l];
            const float x1 = red[(a*5+1) * 64 + l];
            const float x2 = red[(a*5+2) * 64 + l];
            const float x3 = red[(a*5+3) * 64 + l];
            const float x4 = red[(a*5+4) * 64 + l];
            const float px = sigm(x0 + bias[a*NCg+0]) + gxf;
            const float py = sigm(x1 + bias[a*NCg+1]) + gyf;
            const float pw = expf(x2 + bias[a*NCg+2]) * c_AW[a];
            const float ph = expf(x3 + bias[a*NCg+3]) * c_AH[a];
            cf[a]   = sigm(x4 + bias[a*NCg+4]);
            pbx0[a] = px - pw * 0.5f;  pby0[a] = py - ph * 0.5f;
            pbx1[a] = px + pw * 0.5f;  pby1[a] = py + ph * 0.5f;
            pa[a]   = pw * ph;
        }

        // this wave handles boxes n = w, w+4, ...
        const float* gb = gbox + (size_t)b * NBOX * 8;
        for (int n = w; n < NBOX; n += 4) {
            const float bx0 = gb[n*8+0], by0 = gb[n*8+1];
            const float bx1 = gb[n*8+2], by1 = gb[n*8+3];
            const float gar = gb[n*8+4];
            const int cell  = __float_as_int(gb[n*8+5]);
            const int d = cell - s;
            if (d == 0)       mask |= 8;      // assigned, anchor 0
            if (d == NSp)     mask |= 16;     // anchor 1
            if (d == 2*NSp)   mask |= 32;     // anchor 2
            if (gar >= 0.f) {                 // wave-uniform branch
#pragma unroll
                for (int a = 0; a < 3; ++a) {
                    const float tlx = fmaxf(pbx0[a], bx0);
                    const float tly = fmaxf(pby0[a], by0);
                    const float brx = fminf(pbx1[a], bx1);
                    const float bry = fminf(pby1[a], by1);
                    const float dx = brx - tlx, dy = bry - tly;
                    const float inter = (dx > 0.f && dy > 0.f) ? dx * dy : 0.f;
                    // iou > 0.7  <=>  inter > 0.7*union   (no division)
                    if (inter > 0.7f * (pa[a] + gar - inter)) mask |= (1 << a);
                }
            }
        }
    }
    smask[tid] = mask;
    __syncthreads();

    if (w == 0) {
        float lsum = 0.f;
        if (live) {
            const int m = smask[l] | smask[64 + l] | smask[128 + l] | smask[192 + l];
            const bool hasB = hasAny[b] != 0;
#pragma unroll
            for (int a = 0; a < 3; ++a) {
                const bool ex = (m & (1 << a)) != 0;
                const bool as = (m & (8 << a)) != 0;
                const bool maskpre = hasB ? (!ex) : true;
                if (maskpre || as) {
                    const float c = cf[a];
                    lsum += as ? -safe_log(c) : -safe_log(1.f - c);
                }
            }
        }
#pragma unroll
        for (int off = 32; off > 0; off >>= 1) lsum += __shfl_down(lsum, off);
        if (l == 0) atomicAdd(&acc[2], lsum);
    }
}

// ---- Kernel 3: per-assigned-cell xy/wh/cls losses -------------------------
__global__ __launch_bounds__(256) void k_assigned(
    const float* __restrict__ xin, const float* __restrict__ W,
    const float* __restrict__ bias, const float* __restrict__ gaux,
    const int* __restrict__ gint, float* __restrict__ acc)
{
    const int t = blockIdx.x;            // box id 0..799
    const int b = t / NBOX, n = t % NBOX;
    const int tid = threadIdx.x;

    __shared__ int   scell[NBOX];
    __shared__ float4 col4[64];
    __shared__ float  xsh[NCg];
    __shared__ float  sacc[3];

    if (tid < NBOX) scell[tid] = gint[(b * NBOX + tid) * 2];
    __syncthreads();

    const int cell = scell[n];
    if (cell < 0) return;
    // winner = highest box index sharing this cell (last-index-wins)
    for (int n2 = n + 1; n2 < NBOX; ++n2)
        if (scell[n2] == cell) return;

    const int a = cell / NSp, s = cell % NSp;
    const int o0 = a * NCg;

    ((float*)col4)[tid] = xin[((size_t)b * INCH + tid) * NSp + s];
    if (tid < 3) sacc[tid] = 0.f;
    __syncthreads();

    const int wid = tid >> 6, lane = tid & 63;
    for (int o = wid; o < NCg; o += 4) {
        const float4 wv = *(const float4*)&W[(size_t)(o0 + o) * INCH + lane * 4];
        const float4 cv = col4[lane];
        float p = wv.x*cv.x + wv.y*cv.y + wv.z*cv.z + wv.w*cv.w;
        for (int off = 32; off; off >>= 1) p += __shfl_down(p, off);
        if (lane == 0) xsh[o] = p + bias[o0 + o];
    }
    __syncthreads();

    if (tid < NCg) {
        const float* ga = gaux + (size_t)t * 8;
        const float sval = ga[4];
        const int gcls = gint[t*2 + 1];
        float val = xsh[tid];
        float term; int slot;
        if (tid < 2) {                       // xy BCE * sval
            float tgt = ga[tid];
            float p = sigm(val);
            term = -(tgt * safe_log(p) + (1.f - tgt) * safe_log(1.f - p)) * sval;
            slot = 0;
        } else if (tid < 4) {                // wh MSE * 0.5*sval
            float tgt = ga[tid];             // ga[2], ga[3]
            float d = val - tgt;
            term = 0.5f * sval * d * d;
            slot = 1;
        } else if (tid == 4) {               // conf handled in k_main
            term = 0.f; slot = 2;
        } else {                             // cls BCE
            float tgt = ((tid - 5) == gcls) ? 1.f : 0.f;
            float p = sigm(val);
            term = -(tgt * safe_log(p) + (1.f - tgt) * safe_log(1.f - p));
            slot = 2;
        }
        atomicAdd(&sacc[slot], term);
    }
    __syncthreads();
    if (tid == 0) {
        atomicAdd(&acc[0], sacc[0]);
        atomicAdd(&acc[1], sacc[1]);
        atomicAdd(&acc[3], sacc[2]);
    }
}

// ---- Kernel 4: finalize ---------------------------------------------------
__global__ void k_final(const float* __restrict__ acc, float* __restrict__ out)
{
    float xy = acc[0], wh = acc[1], ob = acc[2], cl = acc[3];
    out[0] = xy + wh + ob + cl;
    out[1] = xy; out[2] = wh; out[3] = ob; out[4] = cl;
}

extern "C" void kernel_launch(void* const* d_in, const int* in_sizes, int n_in,
                              void* d_out, int out_size, void* d_ws, size_t ws_size,
                              hipStream_t stream)
{
    const float* xin    = (const float*)d_in[0];
    const float* labels = (const float*)d_in[1];
    const float* W      = (const float*)d_in[2];
    const float* bias   = (const float*)d_in[3];

    char* ws = (char*)d_ws;
    float* acc    = (float*)(ws + ACC_OFF);
    int*   hasAny = (int*)  (ws + HAS_OFF);
    float* Wt     = (float*)(ws + WT_OFF);
    float* gbox   = (float*)(ws + GB_OFF);
    float* gaux   = (float*)(ws + GA_OFF);
    int*   gint   = (int*)  (ws + GI_OFF);
    float* out    = (float*)d_out;

    k_labels<<<16, 256, 0, stream>>>(labels, W, Wt, gbox, gaux, gint, hasAny, acc);

    k_main<<<dim3((NSp + 63) / 64, NB), 256, 0, stream>>>(xin, Wt, bias, gbox, hasAny, acc);

    k_assigned<<<dim3(NB * NBOX), 256, 0, stream>>>(xin, W, bias, gaux, gint, acc);

    k_final<<<1, 1, 0, stream>>>(acc, out);
}

// Round 3
// 194.322 us; speedup vs baseline: 1.2150x; 1.1925x over previous
//
#include <hip/hip_runtime.h>
#include <math.h>

#define NB    16
#define NAg   3
#define NCg   85
#define NCLS  80
#define NGg   76
#define NSp   (NGg*NGg)     // 5776
#define NBOX  50
#define INCH  256
#define NG2   (NSp/2)       // 2888 float2 groups
#define SPB   128           // spatial positions per k_main block
#define GPB   64            // float2 groups per k_main block

// ws layout (bytes)
#define ACC_OFF  0                       // 8 floats  (loss accumulators)
#define HAS_OFF  32                      // 16 ints   (per-batch has_boxes flag)
#define WT_OFF   128                     // 256*16 floats = 16384 B (transposed W, stride 16)
#define GB_OFF   (WT_OFF + 16384)        // NB*NBOX*8 floats = 25600 B (IoU box records)
#define GA_OFF   (GB_OFF + 25600)        // NB*NBOX*8 floats = 25600 B (target aux)
#define GI_OFF   (GA_OFF + 25600)        // NB*NBOX*2 ints   =  6400 B (cell, cls)

__device__ __constant__ float c_AW[9] = {1.25f,2.0f,4.125f,3.75f,7.75f,7.375f,14.5f,19.5f,46.625f};
__device__ __constant__ float c_AH[9] = {1.625f,3.75f,2.875f,7.625f,5.625f,14.875f,11.25f,24.75f,40.75f};

__device__ __forceinline__ float safe_log(float p) {
    return fmaxf(logf(fmaxf(p, 1e-12f)), -100.0f);
}
__device__ __forceinline__ float sigm(float x) {
    return 1.0f / (1.0f + expf(-x));
}

// ---- Kernel 1: label processing + W transpose + acc/hasAny init -----------
__global__ __launch_bounds__(256) void k_labels(
    const float* __restrict__ labels, const float* __restrict__ W,
    float* __restrict__ Wt, float* __restrict__ gbox, float* __restrict__ gaux,
    int* __restrict__ gint, int* __restrict__ hasAny, float* __restrict__ acc)
{
    const int b = blockIdx.x, tid = threadIdx.x;
    const int t = b * 256 + tid;

    // transposed weights: Wt[c*16 + f] = W[row(f)*INCH + c], f<15 (slot 15 pad)
    {
        const int c = t >> 4, f = t & 15;
        Wt[t] = (f < 15) ? W[((f / 5) * NCg + (f % 5)) * INCH + c] : 0.f;
    }
    if (b == 0 && tid < 8) acc[tid] = 0.f;

    int valid = 0;
    if (tid < NBOX) {
        const int bt = b * NBOX + tid;
        const float* L = labels + (size_t)bt * 5;
        const float l0 = L[0], l1 = L[1], l2 = L[2], l3 = L[3], l4 = L[4];
        valid = (l0 + l1 + l2 + l3 + l4) > 0.f;

        const float gx = l1 * NGg, gy = l2 * NGg, gw = l3 * NGg, gh = l4 * NGg;

        int best = 0; float brr = -1.f;
#pragma unroll
        for (int k = 0; k < 9; k++) {
            float inter = fminf(gw, c_AW[k]) * fminf(gh, c_AH[k]);
            float uni   = gw*gh + c_AW[k]*c_AH[k] - inter;
            float r     = inter / uni;
            if (r > brr) { brr = r; best = k; }   // first max wins (argmax)
        }
        const int a = (best <= 2) ? best : -1;
        const int assign = valid && (a >= 0);
        const int a_safe = a < 0 ? 0 : (a > 2 ? 2 : a);

        const int gi = (int)floorf(gx), gj = (int)floorf(gy);
        const int inb = (gi >= 0) && (gi < NGg) && (gj >= 0) && (gj < NGg);
        const int cell = (assign && inb) ? (a * NSp + gj * NGg + gi) : -1;

        float* gb = gbox + (size_t)bt * 8;
        gb[0] = gx - gw * 0.5f;             // x0
        gb[1] = gy - gh * 0.5f;             // y0
        gb[2] = gx + gw * 0.5f;             // x1
        gb[3] = gy + gh * 0.5f;             // y1
        gb[4] = valid ? gw * gh : -1.f;     // area, <0 => skip in IoU
        gb[5] = __int_as_float(cell);       // assigned cell (-1 none)

        float* ga = gaux + (size_t)bt * 8;
        ga[0] = gx - floorf(gx);
        ga[1] = gy - floorf(gy);
        ga[2] = logf(gw / c_AW[a_safe] + 1e-16f);
        ga[3] = logf(gh / c_AH[a_safe] + 1e-16f);
        ga[4] = 2.f - gw * gh / (float)NSp;

        gint[bt*2 + 0] = cell;
        gint[bt*2 + 1] = (int)l0;
    }
    if (tid < 64) {
        const unsigned long long m = __ballot(valid != 0);
        if (tid == 0) hasAny[b] = (m != 0ULL) ? 1 : 0;
    }
}

// ---- Kernel 2: fused 15-ch GEMM + decode + IoU-threshold + obj BCE --------
// 256 threads = 4 waves. Block covers 128 spatial positions (64 float2 groups).
// Wave w reduces channels [64w,64w+64); each wave-load is 512B contiguous.
// Partials combined via LDS; threads 0..127 then decode+IoU one position each.
__global__ __launch_bounds__(256) void k_main(
    const float* __restrict__ xin, const float* __restrict__ Wt,
    const float* __restrict__ bias, const float* __restrict__ gbox,
    const int* __restrict__ hasAny, float* __restrict__ acc)
{
    __shared__ float2 buf[4][15][GPB];   // 30720 B
    __shared__ float  wred[2];

    const int b   = blockIdx.y;
    const int tid = threadIdx.x;
    const int w   = tid >> 6, l = tid & 63;
    const int wu  = __builtin_amdgcn_readfirstlane(w);   // force scalar weight base
    const int G   = blockIdx.x * GPB + l;                // float2 group id
    const bool liveG = (G < NG2);

    float2 a2[15];
#pragma unroll
    for (int f = 0; f < 15; ++f) a2[f] = make_float2(0.f, 0.f);

    if (liveG) {
        const float* xp = xin + ((size_t)b * INCH + (wu << 6)) * NSp + (G << 1);
        const float* wp = Wt + ((wu << 6) << 4);
#pragma unroll 2
        for (int c0 = 0; c0 < 64; c0 += 8) {
            float2 v[8];
#pragma unroll
            for (int k = 0; k < 8; ++k)
                v[k] = *(const float2*)(xp + (size_t)(c0 + k) * NSp);
#pragma unroll
            for (int k = 0; k < 8; ++k) {
                const float* wr = wp + ((c0 + k) << 4);   // wave-uniform -> s_load
#pragma unroll
                for (int f = 0; f < 15; ++f) {
                    a2[f].x += wr[f] * v[k].x;
                    a2[f].y += wr[f] * v[k].y;
                }
            }
        }
    }
#pragma unroll
    for (int f = 0; f < 15; ++f) buf[w][f][l] = a2[f];
    __syncthreads();

    // ---- phase 3: threads 0..127 handle one spatial position each ----
    float lsum = 0.f;
    const int p = blockIdx.x * SPB + tid;
    if (tid < SPB && p < NSp) {
        const int g = tid >> 1, e = tid & 1;
        float xv[15];
#pragma unroll
        for (int f = 0; f < 15; ++f) {
            xv[f] = ((const float*)&buf[0][f][g])[e]
                  + ((const float*)&buf[1][f][g])[e]
                  + ((const float*)&buf[2][f][g])[e]
                  + ((const float*)&buf[3][f][g])[e];
        }

        const int sy = p / NGg;
        const int sx = p - sy * NGg;
        const float gxf = (float)sx, gyf = (float)sy;

        float pbx0[3], pby0[3], pbx1[3], pby1[3], pa[3], cf[3];
#pragma unroll
        for (int a = 0; a < 3; ++a) {
            const float px = sigm(xv[a*5+0] + bias[a*NCg+0]) + gxf;
            const float py = sigm(xv[a*5+1] + bias[a*NCg+1]) + gyf;
            const float pw = expf(xv[a*5+2] + bias[a*NCg+2]) * c_AW[a];
            const float ph = expf(xv[a*5+3] + bias[a*NCg+3]) * c_AH[a];
            cf[a]   = sigm(xv[a*5+4] + bias[a*NCg+4]);
            pbx0[a] = px - pw * 0.5f;  pby0[a] = py - ph * 0.5f;
            pbx1[a] = px + pw * 0.5f;  pby1[a] = py + ph * 0.5f;
            pa[a]   = pw * ph;
        }

        int mask = 0;
        const float* gb = gbox + (size_t)b * NBOX * 8;
        for (int n = 0; n < NBOX; ++n) {
            const float bx0 = gb[n*8+0], by0 = gb[n*8+1];
            const float bx1 = gb[n*8+2], by1 = gb[n*8+3];
            const float gar = gb[n*8+4];
            const int cell  = __float_as_int(gb[n*8+5]);
            const int d = cell - p;
            if (d == 0)       mask |= 8;      // assigned, anchor 0
            if (d == NSp)     mask |= 16;     // anchor 1
            if (d == 2*NSp)   mask |= 32;     // anchor 2
            if (gar >= 0.f) {                 // wave-uniform branch
#pragma unroll
                for (int a = 0; a < 3; ++a) {
                    const float tlx = fmaxf(pbx0[a], bx0);
                    const float tly = fmaxf(pby0[a], by0);
                    const float brx = fminf(pbx1[a], bx1);
                    const float bry = fminf(pby1[a], by1);
                    const float dx = brx - tlx, dy = bry - tly;
                    const float inter = (dx > 0.f && dy > 0.f) ? dx * dy : 0.f;
                    // iou > 0.7  <=>  inter > 0.7*union   (no division)
                    if (inter > 0.7f * (pa[a] + gar - inter)) mask |= (1 << a);
                }
            }
        }

        const bool hasB = hasAny[b] != 0;
#pragma unroll
        for (int a = 0; a < 3; ++a) {
            const bool ex = (mask & (1 << a)) != 0;
            const bool as = (mask & (8 << a)) != 0;
            const bool maskpre = hasB ? (!ex) : true;
            if (maskpre || as) {
                const float c = cf[a];
                lsum += as ? -safe_log(c) : -safe_log(1.f - c);
            }
        }
    }

    // reduce: waves 0,1 carry data; shuffle within wave, cross-wave via LDS
#pragma unroll
    for (int off = 32; off > 0; off >>= 1) lsum += __shfl_down(lsum, off);
    if (w < 2 && l == 0) wred[w] = lsum;
    __syncthreads();
    if (tid == 0) atomicAdd(&acc[2], wred[0] + wred[1]);
}

// ---- Kernel 3: per-assigned-cell xy/wh/cls losses -------------------------
__global__ __launch_bounds__(256) void k_assigned(
    const float* __restrict__ xin, const float* __restrict__ W,
    const float* __restrict__ bias, const float* __restrict__ gaux,
    const int* __restrict__ gint, float* __restrict__ acc)
{
    const int t = blockIdx.x;            // box id 0..799
    const int b = t / NBOX, n = t % NBOX;
    const int tid = threadIdx.x;

    __shared__ int   scell[NBOX];
    __shared__ float4 col4[64];
    __shared__ float  xsh[NCg];
    __shared__ float  sacc[3];

    if (tid < NBOX) scell[tid] = gint[(b * NBOX + tid) * 2];
    __syncthreads();

    const int cell = scell[n];
    if (cell < 0) return;
    // winner = highest box index sharing this cell (last-index-wins)
    for (int n2 = n + 1; n2 < NBOX; ++n2)
        if (scell[n2] == cell) return;

    const int a = cell / NSp, s = cell % NSp;
    const int o0 = a * NCg;

    ((float*)col4)[tid] = xin[((size_t)b * INCH + tid) * NSp + s];
    if (tid < 3) sacc[tid] = 0.f;
    __syncthreads();

    const int wid = tid >> 6, lane = tid & 63;
    for (int o = wid; o < NCg; o += 4) {
        const float4 wv = *(const float4*)&W[(size_t)(o0 + o) * INCH + lane * 4];
        const float4 cv = col4[lane];
        float p = wv.x*cv.x + wv.y*cv.y + wv.z*cv.z + wv.w*cv.w;
        for (int off = 32; off; off >>= 1) p += __shfl_down(p, off);
        if (lane == 0) xsh[o] = p + bias[o0 + o];
    }
    __syncthreads();

    if (tid < NCg) {
        const float* ga = gaux + (size_t)t * 8;
        const float sval = ga[4];
        const int gcls = gint[t*2 + 1];
        float val = xsh[tid];
        float term; int slot;
        if (tid < 2) {                       // xy BCE * sval
            float tgt = ga[tid];
            float p = sigm(val);
            term = -(tgt * safe_log(p) + (1.f - tgt) * safe_log(1.f - p)) * sval;
            slot = 0;
        } else if (tid < 4) {                // wh MSE * 0.5*sval
            float tgt = ga[tid];             // ga[2], ga[3]
            float d = val - tgt;
            term = 0.5f * sval * d * d;
            slot = 1;
        } else if (tid == 4) {               // conf handled in k_main
            term = 0.f; slot = 2;
        } else {                             // cls BCE
            float tgt = ((tid - 5) == gcls) ? 1.f : 0.f;
            float p = sigm(val);
            term = -(tgt * safe_log(p) + (1.f - tgt) * safe_log(1.f - p));
            slot = 2;
        }
        atomicAdd(&sacc[slot], term);
    }
    __syncthreads();
    if (tid == 0) {
        atomicAdd(&acc[0], sacc[0]);
        atomicAdd(&acc[1], sacc[1]);
        atomicAdd(&acc[3], sacc[2]);
    }
}

// ---- Kernel 4: finalize ---------------------------------------------------
__global__ void k_final(const float* __restrict__ acc, float* __restrict__ out)
{
    float xy = acc[0], wh = acc[1], ob = acc[2], cl = acc[3];
    out[0] = xy + wh + ob + cl;
    out[1] = xy; out[2] = wh; out[3] = ob; out[4] = cl;
}

extern "C" void kernel_launch(void* const* d_in, const int* in_sizes, int n_in,
                              void* d_out, int out_size, void* d_ws, size_t ws_size,
                              hipStream_t stream)
{
    const float* xin    = (const float*)d_in[0];
    const float* labels = (const float*)d_in[1];
    const float* W      = (const float*)d_in[2];
    const float* bias   = (const float*)d_in[3];

    char* ws = (char*)d_ws;
    float* acc    = (float*)(ws + ACC_OFF);
    int*   hasAny = (int*)  (ws + HAS_OFF);
    float* Wt     = (float*)(ws + WT_OFF);
    float* gbox   = (float*)(ws + GB_OFF);
    float* gaux   = (float*)(ws + GA_OFF);
    int*   gint   = (int*)  (ws + GI_OFF);
    float* out    = (float*)d_out;

    k_labels<<<16, 256, 0, stream>>>(labels, W, Wt, gbox, gaux, gint, hasAny, acc);

    k_main<<<dim3((NSp + SPB - 1) / SPB, NB), 256, 0, stream>>>(xin, Wt, bias, gbox, hasAny, acc);

    k_assigned<<<dim3(NB * NBOX), 256, 0, stream>>>(xin, W, bias, gaux, gint, acc);

    k_final<<<1, 1, 0, stream>>>(acc, out);
}